// Round 1
// baseline (483.302 us; speedup 1.0000x reference)
//
#include <hip/hip_runtime.h>
#include <math.h>

#define C 128  // IN_C == OUT_C == 128

// ---------------------------------------------------------------------------
// K1: xl = x @ W^T   (x: [N,128], W: [128,128] row-major [out_c][k])
// Block = 256 threads, 32 rows per block. W^T staged in LDS in two K-halves
// (pad 129 -> conflict-free LDS reads/writes), x tile staged in LDS.
// ---------------------------------------------------------------------------
__global__ __launch_bounds__(256) void k_gemm(const float* __restrict__ x,
                                              const float* __restrict__ W,
                                              float* __restrict__ xl, int N) {
    __shared__ float wt[64 * 129];   // wt[k*129 + c] = W[c][half*64 + k]
    __shared__ float xs[32 * 128];
    const int tid = threadIdx.x;
    const int row0 = blockIdx.x * 32;

    for (int i = tid; i < 32 * 128; i += 256) {
        int r = i >> 7, k = i & 127;
        int gr = row0 + r;
        xs[i] = (gr < N) ? x[(size_t)gr * C + k] : 0.0f;
    }

    const int c0 = tid & 31;      // lane column (cols c0 + 32j)
    const int rg = tid >> 5;      // row group (rows 4rg..4rg+3)
    float acc[4][4];
#pragma unroll
    for (int i = 0; i < 4; ++i)
#pragma unroll
        for (int j = 0; j < 4; ++j) acc[i][j] = 0.0f;

    for (int half = 0; half < 2; ++half) {
        __syncthreads();
        for (int i = tid; i < 64 * 128; i += 256) {
            int c = i >> 6, k = i & 63;
            wt[k * 129 + c] = W[c * C + half * 64 + k];
        }
        __syncthreads();
        for (int k = 0; k < 64; ++k) {
            float xv[4], wv[4];
#pragma unroll
            for (int i = 0; i < 4; ++i) xv[i] = xs[(4 * rg + i) * C + half * 64 + k];
#pragma unroll
            for (int j = 0; j < 4; ++j) wv[j] = wt[k * 129 + c0 + 32 * j];
#pragma unroll
            for (int i = 0; i < 4; ++i)
#pragma unroll
                for (int j = 0; j < 4; ++j) acc[i][j] = fmaf(xv[i], wv[j], acc[i][j]);
        }
    }

#pragma unroll
    for (int i = 0; i < 4; ++i) {
        int r = row0 + 4 * rg + i;
        if (r < N) {
#pragma unroll
            for (int j = 0; j < 4; ++j)
                xl[(size_t)r * C + c0 + 32 * j] = acc[i][j];
        }
    }
}

// ---------------------------------------------------------------------------
// K2: per-edge attention logit alpha[e] = emb[src[e]] . emb[dst[e]]
// 16 lanes per edge (each lane 8 floats = 2 float4), shfl reduce within 16.
// ---------------------------------------------------------------------------
__global__ __launch_bounds__(256) void k_alpha(const float* __restrict__ emb,
                                               const int* __restrict__ eidx,
                                               float* __restrict__ alpha, int E) {
    const int g = threadIdx.x >> 4, sub = threadIdx.x & 15;
    const int e = blockIdx.x * 16 + g;
    if (e >= E) return;
    const int s = eidx[e], d = eidx[E + e];
    const float4* ps = (const float4*)(emb + (size_t)s * C) + sub * 2;
    const float4* pd = (const float4*)(emb + (size_t)d * C) + sub * 2;
    float4 a0 = ps[0], a1 = ps[1];
    float4 b0 = pd[0], b1 = pd[1];
    float p = a0.x * b0.x + a0.y * b0.y + a0.z * b0.z + a0.w * b0.w
            + a1.x * b1.x + a1.y * b1.y + a1.z * b1.z + a1.w * b1.w;
#pragma unroll
    for (int o = 8; o >= 1; o >>= 1) p += __shfl_xor(p, o);
    if (sub == 0) alpha[e] = p;
}

// ---------------------------------------------------------------------------
// K3: CSR-by-dst build: histogram -> exclusive scan -> scatter (src, alpha)
// ---------------------------------------------------------------------------
__global__ void k_hist(const int* __restrict__ eidx, int* __restrict__ counts, int E) {
    int e = blockIdx.x * blockDim.x + threadIdx.x;
    if (e < E) atomicAdd(&counts[eidx[E + e]], 1);
}

__global__ __launch_bounds__(1024) void k_scan(const int* __restrict__ counts,
                                               int* __restrict__ offs,
                                               int* __restrict__ cursor, int N) {
    __shared__ int sdata[1024];
    const int t = threadIdx.x;
    const int CH = (N + 1023) >> 10;
    const int lo = t * CH;
    const int hi = min(lo + CH, N);
    int s = 0;
    for (int i = lo; i < hi; ++i) s += counts[i];
    sdata[t] = s;
    __syncthreads();
    for (int o = 1; o < 1024; o <<= 1) {
        int v = (t >= o) ? sdata[t - o] : 0;
        __syncthreads();
        sdata[t] += v;
        __syncthreads();
    }
    int pref = (t == 0) ? 0 : sdata[t - 1];
    for (int i = lo; i < hi; ++i) {
        int cv = counts[i];
        offs[i] = pref;
        cursor[i] = pref;
        pref += cv;
    }
    if (t == 1023) offs[N] = pref;
}

__global__ void k_scatter(const int* __restrict__ eidx, const float* __restrict__ alpha,
                          int* __restrict__ cursor, int* __restrict__ src_s,
                          float* __restrict__ alpha_s, int E) {
    int e = blockIdx.x * blockDim.x + threadIdx.x;
    if (e >= E) return;
    int d = eidx[E + e];
    int pos = atomicAdd(&cursor[d], 1);
    src_s[pos] = eidx[e];
    alpha_s[pos] = alpha[e];
}

// ---------------------------------------------------------------------------
// K4: per-node softmax + aggregation. One wave (64 lanes) per node; lane owns
// channels (2*lane, 2*lane+1). Self-loop alpha = ||emb[node]||^2 handled
// analytically. out = sum_e softmax(alpha)_e * xl[src_e] + bias   (pre-BN)
// ---------------------------------------------------------------------------
__global__ __launch_bounds__(256) void k_agg(const float* __restrict__ xl,
                                             const float* __restrict__ emb,
                                             const float* __restrict__ alpha_s,
                                             const int* __restrict__ src_s,
                                             const int* __restrict__ offs,
                                             const float* __restrict__ bias,
                                             float* __restrict__ out, int N) {
    const int node = (int)((blockIdx.x * (size_t)blockDim.x + threadIdx.x) >> 6);
    const int lane = threadIdx.x & 63;
    if (node >= N) return;
    const int s0 = offs[node], s1 = offs[node + 1];

    // self-loop logit = ||emb[node]||^2
    float2 ev = ((const float2*)(emb + (size_t)node * C))[lane];
    float p = ev.x * ev.x + ev.y * ev.y;
#pragma unroll
    for (int o = 32; o >= 1; o >>= 1) p += __shfl_xor(p, o);
    const float self_a = p;

    // segment max
    float m = self_a;
    for (int e = s0 + lane; e < s1; e += 64) m = fmaxf(m, alpha_s[e]);
#pragma unroll
    for (int o = 32; o >= 1; o >>= 1) m = fmaxf(m, __shfl_xor(m, o));

    // segment sum of exp
    float dsum = 0.0f;
    for (int e = s0 + lane; e < s1; e += 64) dsum += expf(alpha_s[e] - m);
#pragma unroll
    for (int o = 32; o >= 1; o >>= 1) dsum += __shfl_xor(dsum, o);
    const float wself = expf(self_a - m);
    dsum += wself;

    // aggregate: acc = wself*xl[node] + sum_e w_e * xl[src_e]
    float2 xv = ((const float2*)(xl + (size_t)node * C))[lane];
    float2 acc = {wself * xv.x, wself * xv.y};
    for (int e = s0; e < s1; ++e) {
        int s = src_s[e];                    // wave-uniform
        float w = expf(alpha_s[e] - m);      // wave-uniform
        float2 v = ((const float2*)(xl + (size_t)s * C))[lane];
        acc.x = fmaf(w, v.x, acc.x);
        acc.y = fmaf(w, v.y, acc.y);
    }
    const float inv = 1.0f / (dsum + 1e-16f);
    const int c = lane * 2;
    float2 o2;
    o2.x = acc.x * inv + bias[c];
    o2.y = acc.y * inv + bias[c + 1];
    ((float2*)(out + (size_t)node * C))[lane] = o2;
}

// ---------------------------------------------------------------------------
// K5: per-channel BN stats (sum, sumsq) via block partials + atomics
// ---------------------------------------------------------------------------
__global__ __launch_bounds__(256) void k_bnstats(const float* __restrict__ out,
                                                 float* __restrict__ ssum,
                                                 float* __restrict__ ssq, int N) {
    const int c = threadIdx.x & 127, h = threadIdx.x >> 7;
    const int per = (N + gridDim.x - 1) / gridDim.x;
    const int r0 = blockIdx.x * per;
    const int r1 = min(r0 + per, N);
    float s = 0.0f, q = 0.0f;
    for (int r = r0 + h; r < r1; r += 2) {
        float v = out[(size_t)r * C + c];
        s += v;
        q = fmaf(v, v, q);
    }
    __shared__ float ls[256];
    ls[threadIdx.x] = s;
    __syncthreads();
    if (h == 0) atomicAdd(&ssum[c], ls[c] + ls[c + 128]);
    __syncthreads();
    ls[threadIdx.x] = q;
    __syncthreads();
    if (h == 0) atomicAdd(&ssq[c], ls[c] + ls[c + 128]);
}

// ---------------------------------------------------------------------------
// K6: in-place BN apply (training-mode batch stats, biased var) + ReLU
// ---------------------------------------------------------------------------
__global__ __launch_bounds__(256) void k_bnapply(float* __restrict__ out,
                                                 const float* __restrict__ ssum,
                                                 const float* __restrict__ ssq,
                                                 const float* __restrict__ gamma,
                                                 const float* __restrict__ beta,
                                                 int N) {
    const int idx = blockIdx.x * blockDim.x + threadIdx.x;   // float4 index
    const int total = N * (C / 4);
    if (idx >= total) return;
    const int c = (idx * 4) & 127;
    float4 v = ((const float4*)out)[idx];
    const float invN = 1.0f / (float)N;
    float r[4] = {v.x, v.y, v.z, v.w};
#pragma unroll
    for (int j = 0; j < 4; ++j) {
        float mu = ssum[c + j] * invN;
        float var = fmaf(-mu, mu, ssq[c + j] * invN);
        var = fmaxf(var, 0.0f);
        float sc = gamma[c + j] / sqrtf(var + 1e-5f);
        float val = fmaf(r[j] - mu, sc, beta[c + j]);
        r[j] = fmaxf(val, 0.0f);
    }
    float4 o = {r[0], r[1], r[2], r[3]};
    ((float4*)out)[idx] = o;
}

// ---------------------------------------------------------------------------
extern "C" void kernel_launch(void* const* d_in, const int* in_sizes, int n_in,
                              void* d_out, int out_size, void* d_ws, size_t ws_size,
                              hipStream_t stream) {
    const float* x     = (const float*)d_in[0];
    const int*   eidx  = (const int*)d_in[1];   // [2][E] (src row, dst row)
    const float* emb   = (const float*)d_in[2];
    const float* W     = (const float*)d_in[3];
    const float* bias  = (const float*)d_in[4];
    const float* gamma = (const float*)d_in[5];
    const float* beta  = (const float*)d_in[6];
    const int N = in_sizes[0] / C;
    const int E = in_sizes[1] / 2;
    float* out = (float*)d_out;

    char* ws = (char*)d_ws;
    size_t off = 0;
    auto alloc = [&](size_t bytes) -> void* {
        void* p = ws + off;
        off = (off + bytes + 255) & ~(size_t)255;
        return p;
    };
    float* xl      = (float*)alloc((size_t)N * C * 4);
    float* alpha   = (float*)alloc((size_t)E * 4);
    float* alpha_s = (float*)alloc((size_t)E * 4);
    int*   src_s   = (int*)  alloc((size_t)E * 4);
    int*   counts  = (int*)  alloc((size_t)N * 4);
    int*   cursor  = (int*)  alloc((size_t)N * 4);
    int*   offs    = (int*)  alloc((size_t)(N + 1) * 4);
    float* ssum    = (float*)alloc(C * 4);
    float* ssq     = (float*)alloc(C * 4);

    hipMemsetAsync(counts, 0, (size_t)N * 4, stream);
    hipMemsetAsync(ssum, 0, C * 4, stream);
    hipMemsetAsync(ssq, 0, C * 4, stream);

    k_gemm   <<<(N + 31) / 32,    256,  0, stream>>>(x, W, xl, N);
    k_alpha  <<<(E + 15) / 16,    256,  0, stream>>>(emb, eidx, alpha, E);
    k_hist   <<<(E + 255) / 256,  256,  0, stream>>>(eidx, counts, E);
    k_scan   <<<1,                1024, 0, stream>>>(counts, offs, cursor, N);
    k_scatter<<<(E + 255) / 256,  256,  0, stream>>>(eidx, alpha, cursor, src_s, alpha_s, E);
    k_agg    <<<(int)(((size_t)N * 64 + 255) / 256), 256, 0, stream>>>(
                 xl, emb, alpha_s, src_s, offs, bias, out, N);
    k_bnstats<<<512,              256,  0, stream>>>(out, ssum, ssq, N);
    k_bnapply<<<(N * (C / 4) + 255) / 256, 256, 0, stream>>>(out, ssum, ssq, gamma, beta, N);
}

// Round 2
// 378.427 us; speedup vs baseline: 1.2771x; 1.2771x over previous
//
#include <hip/hip_runtime.h>
#include <math.h>

#define C 128  // IN_C == OUT_C == 128

// ---------------------------------------------------------------------------
// K1: xl = x @ W^T   (x: [N,128], W: [128,128] row-major [out_c][k])
// ---------------------------------------------------------------------------
__global__ __launch_bounds__(256) void k_gemm(const float* __restrict__ x,
                                              const float* __restrict__ W,
                                              float* __restrict__ xl, int N) {
    __shared__ float wt[64 * 129];   // wt[k*129 + c] = W[c][half*64 + k]
    __shared__ float xs[32 * 128];
    const int tid = threadIdx.x;
    const int row0 = blockIdx.x * 32;

    for (int i = tid; i < 32 * 128; i += 256) {
        int r = i >> 7, k = i & 127;
        int gr = row0 + r;
        xs[i] = (gr < N) ? x[(size_t)gr * C + k] : 0.0f;
    }

    const int c0 = tid & 31;      // lane column (cols c0 + 32j)
    const int rg = tid >> 5;      // row group (rows 4rg..4rg+3)
    float acc[4][4];
#pragma unroll
    for (int i = 0; i < 4; ++i)
#pragma unroll
        for (int j = 0; j < 4; ++j) acc[i][j] = 0.0f;

    for (int half = 0; half < 2; ++half) {
        __syncthreads();
        for (int i = tid; i < 64 * 128; i += 256) {
            int c = i >> 6, k = i & 63;
            wt[k * 129 + c] = W[c * C + half * 64 + k];
        }
        __syncthreads();
        for (int k = 0; k < 64; ++k) {
            float xv[4], wv[4];
#pragma unroll
            for (int i = 0; i < 4; ++i) xv[i] = xs[(4 * rg + i) * C + half * 64 + k];
#pragma unroll
            for (int j = 0; j < 4; ++j) wv[j] = wt[k * 129 + c0 + 32 * j];
#pragma unroll
            for (int i = 0; i < 4; ++i)
#pragma unroll
                for (int j = 0; j < 4; ++j) acc[i][j] = fmaf(xv[i], wv[j], acc[i][j]);
        }
    }

#pragma unroll
    for (int i = 0; i < 4; ++i) {
        int r = row0 + 4 * rg + i;
        if (r < N) {
#pragma unroll
            for (int j = 0; j < 4; ++j)
                xl[(size_t)r * C + c0 + 32 * j] = acc[i][j];
        }
    }
}

// ---------------------------------------------------------------------------
// K2: per-edge attention logit alpha[e] = emb[src[e]] . emb[dst[e]]
// ---------------------------------------------------------------------------
__global__ __launch_bounds__(256) void k_alpha(const float* __restrict__ emb,
                                               const int* __restrict__ eidx,
                                               float* __restrict__ alpha, int E) {
    const int g = threadIdx.x >> 4, sub = threadIdx.x & 15;
    const int e = blockIdx.x * 16 + g;
    if (e >= E) return;
    const int s = eidx[e], d = eidx[E + e];
    const float4* ps = (const float4*)(emb + (size_t)s * C) + sub * 2;
    const float4* pd = (const float4*)(emb + (size_t)d * C) + sub * 2;
    float4 a0 = ps[0], a1 = ps[1];
    float4 b0 = pd[0], b1 = pd[1];
    float p = a0.x * b0.x + a0.y * b0.y + a0.z * b0.z + a0.w * b0.w
            + a1.x * b1.x + a1.y * b1.y + a1.z * b1.z + a1.w * b1.w;
#pragma unroll
    for (int o = 8; o >= 1; o >>= 1) p += __shfl_xor(p, o);
    if (sub == 0) alpha[e] = p;
}

// ---------------------------------------------------------------------------
// K3: CSR-by-dst build: histogram -> hierarchical exclusive scan -> scatter
// ---------------------------------------------------------------------------
__global__ void k_hist(const int* __restrict__ eidx, int* __restrict__ counts, int E) {
    int e = blockIdx.x * blockDim.x + threadIdx.x;
    if (e < E) atomicAdd(&counts[eidx[E + e]], 1);
}

// scanA: per-block (1024 elems) local exclusive scan -> offs, block sum -> bsums
__global__ __launch_bounds__(256) void k_scanA(const int* __restrict__ counts,
                                               int* __restrict__ offs,
                                               int* __restrict__ bsums, int N) {
    __shared__ int ts[256];
    const int t = threadIdx.x;
    const int base = blockIdx.x * 1024 + t * 4;
    int v[4];
    int s = 0;
#pragma unroll
    for (int j = 0; j < 4; ++j) {
        v[j] = (base + j < N) ? counts[base + j] : 0;
        s += v[j];
    }
    ts[t] = s;
    __syncthreads();
    for (int o = 1; o < 256; o <<= 1) {
        int u = (t >= o) ? ts[t - o] : 0;
        __syncthreads();
        ts[t] += u;
        __syncthreads();
    }
    int pref = (t == 0) ? 0 : ts[t - 1];
    if (t == 255) bsums[blockIdx.x] = ts[255];
#pragma unroll
    for (int j = 0; j < 4; ++j) {
        if (base + j < N) offs[base + j] = pref;
        pref += v[j];
    }
}

// scanB: single block exclusive-scans block sums (nb <= 256); writes total to offs[N]
__global__ __launch_bounds__(256) void k_scanB(int* __restrict__ bsums,
                                               int* __restrict__ offs_total, int nb) {
    __shared__ int ts[256];
    const int t = threadIdx.x;
    int v = (t < nb) ? bsums[t] : 0;
    ts[t] = v;
    __syncthreads();
    for (int o = 1; o < 256; o <<= 1) {
        int u = (t >= o) ? ts[t - o] : 0;
        __syncthreads();
        ts[t] += u;
        __syncthreads();
    }
    if (t < nb) bsums[t] = ts[t] - v;   // exclusive
    if (t == 255) *offs_total = ts[255];
}

// scanC: offs[i] += bsums[block(i)]; cursor[i] = offs[i]
__global__ __launch_bounds__(256) void k_scanC(int* __restrict__ offs,
                                               int* __restrict__ cursor,
                                               const int* __restrict__ bsums, int N) {
    int i = blockIdx.x * 256 + threadIdx.x;
    if (i >= N) return;
    int o = offs[i] + bsums[i >> 10];
    offs[i] = o;
    cursor[i] = o;
}

__global__ void k_scatter(const int* __restrict__ eidx, const float* __restrict__ alpha,
                          int* __restrict__ cursor, int* __restrict__ src_s,
                          float* __restrict__ alpha_s, int E) {
    int e = blockIdx.x * blockDim.x + threadIdx.x;
    if (e >= E) return;
    int d = eidx[E + e];
    int pos = atomicAdd(&cursor[d], 1);
    src_s[pos] = eidx[e];
    alpha_s[pos] = alpha[e];
}

// ---------------------------------------------------------------------------
// K4: per-node softmax + aggregation. One wave per node; lane owns 2 channels.
// ---------------------------------------------------------------------------
__global__ __launch_bounds__(256) void k_agg(const float* __restrict__ xl,
                                             const float* __restrict__ emb,
                                             const float* __restrict__ alpha_s,
                                             const int* __restrict__ src_s,
                                             const int* __restrict__ offs,
                                             const float* __restrict__ bias,
                                             float* __restrict__ out, int N) {
    const int node = (int)((blockIdx.x * (size_t)blockDim.x + threadIdx.x) >> 6);
    const int lane = threadIdx.x & 63;
    if (node >= N) return;
    const int s0 = offs[node], s1 = offs[node + 1];

    // self-loop logit = ||emb[node]||^2
    float2 ev = ((const float2*)(emb + (size_t)node * C))[lane];
    float p = ev.x * ev.x + ev.y * ev.y;
#pragma unroll
    for (int o = 32; o >= 1; o >>= 1) p += __shfl_xor(p, o);
    const float self_a = p;

    // segment max
    float m = self_a;
    for (int e = s0 + lane; e < s1; e += 64) m = fmaxf(m, alpha_s[e]);
#pragma unroll
    for (int o = 32; o >= 1; o >>= 1) m = fmaxf(m, __shfl_xor(m, o));

    // segment sum of exp
    float dsum = 0.0f;
    for (int e = s0 + lane; e < s1; e += 64) dsum += expf(alpha_s[e] - m);
#pragma unroll
    for (int o = 32; o >= 1; o >>= 1) dsum += __shfl_xor(dsum, o);
    const float wself = expf(self_a - m);
    dsum += wself;

    // aggregate: acc = wself*xl[node] + sum_e w_e * xl[src_e]
    float2 xv = ((const float2*)(xl + (size_t)node * C))[lane];
    float2 acc = {wself * xv.x, wself * xv.y};
    for (int e = s0; e < s1; ++e) {
        int s = src_s[e];                    // wave-uniform
        float w = expf(alpha_s[e] - m);      // wave-uniform
        float2 v = ((const float2*)(xl + (size_t)s * C))[lane];
        acc.x = fmaf(w, v.x, acc.x);
        acc.y = fmaf(w, v.y, acc.y);
    }
    const float inv = 1.0f / (dsum + 1e-16f);
    const int c = lane * 2;
    float2 o2;
    o2.x = acc.x * inv + bias[c];
    o2.y = acc.y * inv + bias[c + 1];
    ((float2*)(out + (size_t)node * C))[lane] = o2;
}

// ---------------------------------------------------------------------------
// K5: per-channel BN stats (sum, sumsq) via block partials + atomics
// ---------------------------------------------------------------------------
__global__ __launch_bounds__(256) void k_bnstats(const float* __restrict__ out,
                                                 float* __restrict__ ssum,
                                                 float* __restrict__ ssq, int N) {
    const int c = threadIdx.x & 127, h = threadIdx.x >> 7;
    const int per = (N + gridDim.x - 1) / gridDim.x;
    const int r0 = blockIdx.x * per;
    const int r1 = min(r0 + per, N);
    float s = 0.0f, q = 0.0f;
    for (int r = r0 + h; r < r1; r += 2) {
        float v = out[(size_t)r * C + c];
        s += v;
        q = fmaf(v, v, q);
    }
    __shared__ float ls[256];
    ls[threadIdx.x] = s;
    __syncthreads();
    if (h == 0) atomicAdd(&ssum[c], ls[c] + ls[c + 128]);
    __syncthreads();
    ls[threadIdx.x] = q;
    __syncthreads();
    if (h == 0) atomicAdd(&ssq[c], ls[c] + ls[c + 128]);
}

// ---------------------------------------------------------------------------
// K6: in-place BN apply (training-mode batch stats, biased var) + ReLU
// ---------------------------------------------------------------------------
__global__ __launch_bounds__(256) void k_bnapply(float* __restrict__ out,
                                                 const float* __restrict__ ssum,
                                                 const float* __restrict__ ssq,
                                                 const float* __restrict__ gamma,
                                                 const float* __restrict__ beta,
                                                 int N) {
    const int idx = blockIdx.x * blockDim.x + threadIdx.x;   // float4 index
    const int total = N * (C / 4);
    if (idx >= total) return;
    const int c = (idx * 4) & 127;
    float4 v = ((const float4*)out)[idx];
    const float invN = 1.0f / (float)N;
    float r[4] = {v.x, v.y, v.z, v.w};
#pragma unroll
    for (int j = 0; j < 4; ++j) {
        float mu = ssum[c + j] * invN;
        float var = fmaf(-mu, mu, ssq[c + j] * invN);
        var = fmaxf(var, 0.0f);
        float sc = gamma[c + j] / sqrtf(var + 1e-5f);
        float val = fmaf(r[j] - mu, sc, beta[c + j]);
        r[j] = fmaxf(val, 0.0f);
    }
    float4 o = {r[0], r[1], r[2], r[3]};
    ((float4*)out)[idx] = o;
}

// ---------------------------------------------------------------------------
extern "C" void kernel_launch(void* const* d_in, const int* in_sizes, int n_in,
                              void* d_out, int out_size, void* d_ws, size_t ws_size,
                              hipStream_t stream) {
    const float* x     = (const float*)d_in[0];
    const int*   eidx  = (const int*)d_in[1];   // [2][E] (src row, dst row)
    const float* emb   = (const float*)d_in[2];
    const float* W     = (const float*)d_in[3];
    const float* bias  = (const float*)d_in[4];
    const float* gamma = (const float*)d_in[5];
    const float* beta  = (const float*)d_in[6];
    const int N = in_sizes[0] / C;
    const int E = in_sizes[1] / 2;
    float* out = (float*)d_out;

    char* ws = (char*)d_ws;
    size_t off = 0;
    auto alloc = [&](size_t bytes) -> void* {
        void* p = ws + off;
        off = (off + bytes + 255) & ~(size_t)255;
        return p;
    };
    float* xl      = (float*)alloc((size_t)N * C * 4);
    float* alpha   = (float*)alloc((size_t)E * 4);
    float* alpha_s = (float*)alloc((size_t)E * 4);
    int*   src_s   = (int*)  alloc((size_t)E * 4);
    int*   counts  = (int*)  alloc((size_t)N * 4);
    int*   cursor  = (int*)  alloc((size_t)N * 4);
    int*   offs    = (int*)  alloc((size_t)(N + 1) * 4);
    int*   bsums   = (int*)  alloc(256 * 4);
    float* ssum    = (float*)alloc(C * 4);
    float* ssq     = (float*)alloc(C * 4);

    const int nScanBlocks = (N + 1023) / 1024;   // 49 for N=50000

    hipMemsetAsync(counts, 0, (size_t)N * 4, stream);
    hipMemsetAsync(ssum, 0, C * 4, stream);
    hipMemsetAsync(ssq, 0, C * 4, stream);

    k_gemm   <<<(N + 31) / 32,    256, 0, stream>>>(x, W, xl, N);
    k_alpha  <<<(E + 15) / 16,    256, 0, stream>>>(emb, eidx, alpha, E);
    k_hist   <<<(E + 255) / 256,  256, 0, stream>>>(eidx, counts, E);
    k_scanA  <<<nScanBlocks,      256, 0, stream>>>(counts, offs, bsums, N);
    k_scanB  <<<1,                256, 0, stream>>>(bsums, offs + N, nScanBlocks);
    k_scanC  <<<(N + 255) / 256,  256, 0, stream>>>(offs, cursor, bsums, N);
    k_scatter<<<(E + 255) / 256,  256, 0, stream>>>(eidx, alpha, cursor, src_s, alpha_s, E);
    k_agg    <<<(int)(((size_t)N * 64 + 255) / 256), 256, 0, stream>>>(
                 xl, emb, alpha_s, src_s, offs, bias, out, N);
    k_bnstats<<<512,              256, 0, stream>>>(out, ssum, ssq, N);
    k_bnapply<<<(N * (C / 4) + 255) / 256, 256, 0, stream>>>(out, ssum, ssq, gamma, beta, N);
}

// Round 3
// 295.826 us; speedup vs baseline: 1.6337x; 1.2792x over previous
//
#include <hip/hip_runtime.h>
#include <math.h>

#define C 128  // IN_C == OUT_C == 128

static __device__ __forceinline__ unsigned short f2bf(float f) {
    unsigned int u = __float_as_uint(f);
    u += 0x7FFFu + ((u >> 16) & 1u);   // round-to-nearest-even
    return (unsigned short)(u >> 16);
}
static __device__ __forceinline__ float bf2f(unsigned short h) {
    return __uint_as_float(((unsigned int)h) << 16);
}

// ---------------------------------------------------------------------------
// K1: xl = x @ W^T  -> bf16 output table for the gather phase
// ---------------------------------------------------------------------------
__global__ __launch_bounds__(256) void k_gemm(const float* __restrict__ x,
                                              const float* __restrict__ W,
                                              unsigned short* __restrict__ xlb, int N) {
    __shared__ float wt[64 * 129];   // wt[k*129 + c] = W[c][half*64 + k]
    __shared__ float xs[32 * 128];
    const int tid = threadIdx.x;
    const int row0 = blockIdx.x * 32;

    for (int i = tid; i < 32 * 128; i += 256) {
        int r = i >> 7, k = i & 127;
        int gr = row0 + r;
        xs[i] = (gr < N) ? x[(size_t)gr * C + k] : 0.0f;
    }

    const int c0 = tid & 31;
    const int rg = tid >> 5;
    float acc[4][4];
#pragma unroll
    for (int i = 0; i < 4; ++i)
#pragma unroll
        for (int j = 0; j < 4; ++j) acc[i][j] = 0.0f;

    for (int half = 0; half < 2; ++half) {
        __syncthreads();
        for (int i = tid; i < 64 * 128; i += 256) {
            int c = i >> 6, k = i & 63;
            wt[k * 129 + c] = W[c * C + half * 64 + k];
        }
        __syncthreads();
        for (int k = 0; k < 64; ++k) {
            float xv[4], wv[4];
#pragma unroll
            for (int i = 0; i < 4; ++i) xv[i] = xs[(4 * rg + i) * C + half * 64 + k];
#pragma unroll
            for (int j = 0; j < 4; ++j) wv[j] = wt[k * 129 + c0 + 32 * j];
#pragma unroll
            for (int i = 0; i < 4; ++i)
#pragma unroll
                for (int j = 0; j < 4; ++j) acc[i][j] = fmaf(xv[i], wv[j], acc[i][j]);
        }
    }

#pragma unroll
    for (int i = 0; i < 4; ++i) {
        int r = row0 + 4 * rg + i;
        if (r < N) {
#pragma unroll
            for (int j = 0; j < 4; ++j)
                xlb[(size_t)r * C + c0 + 32 * j] = f2bf(acc[i][j]);
        }
    }
}

// ---------------------------------------------------------------------------
// K3: CSR-by-dst build: histogram -> hierarchical exclusive scan -> scatter
// ---------------------------------------------------------------------------
__global__ void k_hist(const int* __restrict__ eidx, int* __restrict__ counts, int E) {
    int e = blockIdx.x * blockDim.x + threadIdx.x;
    if (e < E) atomicAdd(&counts[eidx[E + e]], 1);
}

__global__ __launch_bounds__(256) void k_scanA(const int* __restrict__ counts,
                                               int* __restrict__ offs,
                                               int* __restrict__ bsums, int N) {
    __shared__ int ts[256];
    const int t = threadIdx.x;
    const int base = blockIdx.x * 1024 + t * 4;
    int v[4];
    int s = 0;
#pragma unroll
    for (int j = 0; j < 4; ++j) {
        v[j] = (base + j < N) ? counts[base + j] : 0;
        s += v[j];
    }
    ts[t] = s;
    __syncthreads();
    for (int o = 1; o < 256; o <<= 1) {
        int u = (t >= o) ? ts[t - o] : 0;
        __syncthreads();
        ts[t] += u;
        __syncthreads();
    }
    int pref = (t == 0) ? 0 : ts[t - 1];
    if (t == 255) bsums[blockIdx.x] = ts[255];
#pragma unroll
    for (int j = 0; j < 4; ++j) {
        if (base + j < N) offs[base + j] = pref;
        pref += v[j];
    }
}

__global__ __launch_bounds__(256) void k_scanB(int* __restrict__ bsums,
                                               int* __restrict__ offs_total, int nb) {
    __shared__ int ts[256];
    const int t = threadIdx.x;
    int v = (t < nb) ? bsums[t] : 0;
    ts[t] = v;
    __syncthreads();
    for (int o = 1; o < 256; o <<= 1) {
        int u = (t >= o) ? ts[t - o] : 0;
        __syncthreads();
        ts[t] += u;
        __syncthreads();
    }
    if (t < nb) bsums[t] = ts[t] - v;   // exclusive
    if (t == 255) *offs_total = ts[255];
}

__global__ __launch_bounds__(256) void k_scanC(int* __restrict__ offs,
                                               int* __restrict__ cursor,
                                               const int* __restrict__ bsums, int N) {
    int i = blockIdx.x * 256 + threadIdx.x;
    if (i >= N) return;
    int o = offs[i] + bsums[i >> 10];
    offs[i] = o;
    cursor[i] = o;
}

__global__ void k_scatter(const int* __restrict__ eidx, int* __restrict__ cursor,
                          int* __restrict__ src_s, int E) {
    int e = blockIdx.x * blockDim.x + threadIdx.x;
    if (e >= E) return;
    int d = eidx[E + e];
    int pos = atomicAdd(&cursor[d], 1);
    src_s[pos] = eidx[e];
}

// ---------------------------------------------------------------------------
// K4: fused per-node attention + online softmax + aggregation.
// One wave per node. Lane owns channels (2l, 2l+1). emb[node] held in regs;
// per edge: gather emb[src] (fp32, 512B) -> dot -> wave reduce; gather
// xl[src] (bf16, 256B) -> online-softmax accumulate. Self-loop analytic.
// ---------------------------------------------------------------------------
__global__ __launch_bounds__(256) void k_agg(const unsigned int* __restrict__ xlb,
                                             const float* __restrict__ emb,
                                             const int* __restrict__ src_s,
                                             const int* __restrict__ offs,
                                             const float* __restrict__ bias,
                                             float* __restrict__ out, int N) {
    const int node = (int)((blockIdx.x * (size_t)blockDim.x + threadIdx.x) >> 6);
    const int lane = threadIdx.x & 63;
    if (node >= N) return;
    const int s0 = offs[node], s1 = offs[node + 1];

    const float2 ed = ((const float2*)(emb + (size_t)node * C))[lane];

    // self-loop logit = ||emb[node]||^2
    float p = ed.x * ed.x + ed.y * ed.y;
#pragma unroll
    for (int o = 32; o >= 1; o >>= 1) p += __shfl_xor(p, o);

    float m = p;        // running max (self included)
    float d = 1.0f;     // exp(self - m) = 1
    unsigned int xw = xlb[(size_t)node * (C / 2) + lane];
    float2 acc;
    acc.x = __uint_as_float(xw << 16);
    acc.y = __uint_as_float(xw & 0xFFFF0000u);

    for (int base = s0; base < s1; base += 64) {
        const int cnt = min(64, s1 - base);
        int mysrc = (lane < cnt) ? src_s[base + lane] : 0;
        for (int i = 0; i < cnt; ++i) {
            const int s = __shfl(mysrc, i);
            const float2 es = ((const float2*)(emb + (size_t)s * C))[lane];
            const unsigned int xv = xlb[(size_t)s * (C / 2) + lane];
            float a = ed.x * es.x + ed.y * es.y;
#pragma unroll
            for (int o = 32; o >= 1; o >>= 1) a += __shfl_xor(a, o);
            if (a > m) {                       // wave-uniform branch
                const float cs = __expf(m - a);
                d *= cs;
                acc.x *= cs;
                acc.y *= cs;
                m = a;
            }
            const float w = __expf(a - m);
            d += w;
            acc.x = fmaf(w, __uint_as_float(xv << 16), acc.x);
            acc.y = fmaf(w, __uint_as_float(xv & 0xFFFF0000u), acc.y);
        }
    }

    const float inv = 1.0f / (d + 1e-16f);
    const int c = lane * 2;
    float2 o2;
    o2.x = fmaf(acc.x, inv, bias[c]);
    o2.y = fmaf(acc.y, inv, bias[c + 1]);
    ((float2*)(out + (size_t)node * C))[lane] = o2;
}

// ---------------------------------------------------------------------------
// K5: per-channel BN stats (sum, sumsq) via block partials + atomics
// ---------------------------------------------------------------------------
__global__ __launch_bounds__(256) void k_bnstats(const float* __restrict__ out,
                                                 float* __restrict__ ssum,
                                                 float* __restrict__ ssq, int N) {
    const int c = threadIdx.x & 127, h = threadIdx.x >> 7;
    const int per = (N + gridDim.x - 1) / gridDim.x;
    const int r0 = blockIdx.x * per;
    const int r1 = min(r0 + per, N);
    float s = 0.0f, q = 0.0f;
    for (int r = r0 + h; r < r1; r += 2) {
        float v = out[(size_t)r * C + c];
        s += v;
        q = fmaf(v, v, q);
    }
    __shared__ float ls[256];
    ls[threadIdx.x] = s;
    __syncthreads();
    if (h == 0) atomicAdd(&ssum[c], ls[c] + ls[c + 128]);
    __syncthreads();
    ls[threadIdx.x] = q;
    __syncthreads();
    if (h == 0) atomicAdd(&ssq[c], ls[c] + ls[c + 128]);
}

// ---------------------------------------------------------------------------
// K6: in-place BN apply (training-mode batch stats, biased var) + ReLU
// ---------------------------------------------------------------------------
__global__ __launch_bounds__(256) void k_bnapply(float* __restrict__ out,
                                                 const float* __restrict__ ssum,
                                                 const float* __restrict__ ssq,
                                                 const float* __restrict__ gamma,
                                                 const float* __restrict__ beta,
                                                 int N) {
    const int idx = blockIdx.x * blockDim.x + threadIdx.x;   // float4 index
    const int total = N * (C / 4);
    if (idx >= total) return;
    const int c = (idx * 4) & 127;
    float4 v = ((const float4*)out)[idx];
    const float invN = 1.0f / (float)N;
    float r[4] = {v.x, v.y, v.z, v.w};
#pragma unroll
    for (int j = 0; j < 4; ++j) {
        float mu = ssum[c + j] * invN;
        float var = fmaf(-mu, mu, ssq[c + j] * invN);
        var = fmaxf(var, 0.0f);
        float sc = gamma[c + j] / sqrtf(var + 1e-5f);
        float val = fmaf(r[j] - mu, sc, beta[c + j]);
        r[j] = fmaxf(val, 0.0f);
    }
    float4 o = {r[0], r[1], r[2], r[3]};
    ((float4*)out)[idx] = o;
}

// ---------------------------------------------------------------------------
extern "C" void kernel_launch(void* const* d_in, const int* in_sizes, int n_in,
                              void* d_out, int out_size, void* d_ws, size_t ws_size,
                              hipStream_t stream) {
    const float* x     = (const float*)d_in[0];
    const int*   eidx  = (const int*)d_in[1];   // [2][E]
    const float* emb   = (const float*)d_in[2];
    const float* W     = (const float*)d_in[3];
    const float* bias  = (const float*)d_in[4];
    const float* gamma = (const float*)d_in[5];
    const float* beta  = (const float*)d_in[6];
    const int N = in_sizes[0] / C;
    const int E = in_sizes[1] / 2;
    float* out = (float*)d_out;

    char* ws = (char*)d_ws;
    size_t off = 0;
    auto alloc = [&](size_t bytes) -> void* {
        void* p = ws + off;
        off = (off + bytes + 255) & ~(size_t)255;
        return p;
    };
    unsigned short* xlb = (unsigned short*)alloc((size_t)N * C * 2);
    int*   src_s   = (int*)  alloc((size_t)E * 4);
    int*   counts  = (int*)  alloc((size_t)N * 4);
    int*   cursor  = (int*)  alloc((size_t)N * 4);
    int*   offs    = (int*)  alloc((size_t)(N + 1) * 4);
    int*   bsums   = (int*)  alloc(256 * 4);
    float* ssum    = (float*)alloc(C * 4);
    float* ssq     = (float*)alloc(C * 4);

    const int nScanBlocks = (N + 1023) / 1024;   // 49 for N=50000

    hipMemsetAsync(counts, 0, (size_t)N * 4, stream);
    hipMemsetAsync(ssum, 0, C * 4, stream);
    hipMemsetAsync(ssq, 0, C * 4, stream);

    k_gemm   <<<(N + 31) / 32,    256, 0, stream>>>(x, W, xlb, N);
    k_hist   <<<(E + 255) / 256,  256, 0, stream>>>(eidx, counts, E);
    k_scanA  <<<nScanBlocks,      256, 0, stream>>>(counts, offs, bsums, N);
    k_scanB  <<<1,                256, 0, stream>>>(bsums, offs + N, nScanBlocks);
    k_scanC  <<<(N + 255) / 256,  256, 0, stream>>>(offs, cursor, bsums, N);
    k_scatter<<<(E + 255) / 256,  256, 0, stream>>>(eidx, cursor, src_s, E);
    k_agg    <<<(int)(((size_t)N * 64 + 255) / 256), 256, 0, stream>>>(
                 (const unsigned int*)xlb, emb, src_s, offs, bias, out, N);
    k_bnstats<<<512,              256, 0, stream>>>(out, ssum, ssq, N);
    k_bnapply<<<(N * (C / 4) + 255) / 256, 256, 0, stream>>>(out, ssum, ssq, gamma, beta, N);
}

// Round 4
// 262.380 us; speedup vs baseline: 1.8420x; 1.1275x over previous
//
#include <hip/hip_runtime.h>
#include <math.h>

#define C 128  // IN_C == OUT_C == 128

static __device__ __forceinline__ unsigned short f2bf(float f) {
    unsigned int u = __float_as_uint(f);
    u += 0x7FFFu + ((u >> 16) & 1u);   // round-to-nearest-even
    return (unsigned short)(u >> 16);
}
static __device__ __forceinline__ float bflo(unsigned int u) {
    return __uint_as_float(u << 16);
}
static __device__ __forceinline__ float bfhi(unsigned int u) {
    return __uint_as_float(u & 0xFFFF0000u);
}

// ---------------------------------------------------------------------------
// K0: emb (f32) -> embb (bf16), packed 2/u32
// ---------------------------------------------------------------------------
__global__ __launch_bounds__(256) void k_embcast(const float* __restrict__ emb,
                                                 unsigned int* __restrict__ embb,
                                                 int total8) {
    int i = blockIdx.x * 256 + threadIdx.x;   // one thread = 8 elems
    if (i >= total8) return;
    const float4 a = ((const float4*)emb)[i * 2];
    const float4 b = ((const float4*)emb)[i * 2 + 1];
    uint4 o;
    o.x = ((unsigned int)f2bf(a.y) << 16) | f2bf(a.x);
    o.y = ((unsigned int)f2bf(a.w) << 16) | f2bf(a.z);
    o.z = ((unsigned int)f2bf(b.y) << 16) | f2bf(b.x);
    o.w = ((unsigned int)f2bf(b.w) << 16) | f2bf(b.z);
    ((uint4*)embb)[i] = o;
}

// ---------------------------------------------------------------------------
// K1: xl = x @ W^T  -> bf16 table
// ---------------------------------------------------------------------------
__global__ __launch_bounds__(256) void k_gemm(const float* __restrict__ x,
                                              const float* __restrict__ W,
                                              unsigned short* __restrict__ xlb, int N) {
    __shared__ float wt[64 * 129];   // wt[k*129 + c] = W[c][half*64 + k]
    __shared__ float xs[32 * 128];
    const int tid = threadIdx.x;
    const int row0 = blockIdx.x * 32;

    for (int i = tid; i < 32 * 128; i += 256) {
        int r = i >> 7, k = i & 127;
        int gr = row0 + r;
        xs[i] = (gr < N) ? x[(size_t)gr * C + k] : 0.0f;
    }

    const int c0 = tid & 31;
    const int rg = tid >> 5;
    float acc[4][4];
#pragma unroll
    for (int i = 0; i < 4; ++i)
#pragma unroll
        for (int j = 0; j < 4; ++j) acc[i][j] = 0.0f;

    for (int half = 0; half < 2; ++half) {
        __syncthreads();
        for (int i = tid; i < 64 * 128; i += 256) {
            int c = i >> 6, k = i & 63;
            wt[k * 129 + c] = W[c * C + half * 64 + k];
        }
        __syncthreads();
        for (int k = 0; k < 64; ++k) {
            float xv[4], wv[4];
#pragma unroll
            for (int i = 0; i < 4; ++i) xv[i] = xs[(4 * rg + i) * C + half * 64 + k];
#pragma unroll
            for (int j = 0; j < 4; ++j) wv[j] = wt[k * 129 + c0 + 32 * j];
#pragma unroll
            for (int i = 0; i < 4; ++i)
#pragma unroll
                for (int j = 0; j < 4; ++j) acc[i][j] = fmaf(xv[i], wv[j], acc[i][j]);
        }
    }

#pragma unroll
    for (int i = 0; i < 4; ++i) {
        int r = row0 + 4 * rg + i;
        if (r < N) {
#pragma unroll
            for (int j = 0; j < 4; ++j)
                xlb[(size_t)r * C + c0 + 32 * j] = f2bf(acc[i][j]);
        }
    }
}

// ---------------------------------------------------------------------------
// K3: CSR-by-dst build: histogram -> hierarchical exclusive scan -> scatter
// ---------------------------------------------------------------------------
__global__ void k_hist(const int* __restrict__ eidx, int* __restrict__ counts, int E) {
    int e = blockIdx.x * blockDim.x + threadIdx.x;
    if (e < E) atomicAdd(&counts[eidx[E + e]], 1);
}

__global__ __launch_bounds__(256) void k_scanA(const int* __restrict__ counts,
                                               int* __restrict__ offs,
                                               int* __restrict__ bsums, int N) {
    __shared__ int ts[256];
    const int t = threadIdx.x;
    const int base = blockIdx.x * 1024 + t * 4;
    int v[4];
    int s = 0;
#pragma unroll
    for (int j = 0; j < 4; ++j) {
        v[j] = (base + j < N) ? counts[base + j] : 0;
        s += v[j];
    }
    ts[t] = s;
    __syncthreads();
    for (int o = 1; o < 256; o <<= 1) {
        int u = (t >= o) ? ts[t - o] : 0;
        __syncthreads();
        ts[t] += u;
        __syncthreads();
    }
    int pref = (t == 0) ? 0 : ts[t - 1];
    if (t == 255) bsums[blockIdx.x] = ts[255];
#pragma unroll
    for (int j = 0; j < 4; ++j) {
        if (base + j < N) offs[base + j] = pref;
        pref += v[j];
    }
}

__global__ __launch_bounds__(256) void k_scanB(int* __restrict__ bsums,
                                               int* __restrict__ offs_total, int nb) {
    __shared__ int ts[256];
    const int t = threadIdx.x;
    int v = (t < nb) ? bsums[t] : 0;
    ts[t] = v;
    __syncthreads();
    for (int o = 1; o < 256; o <<= 1) {
        int u = (t >= o) ? ts[t - o] : 0;
        __syncthreads();
        ts[t] += u;
        __syncthreads();
    }
    if (t < nb) bsums[t] = ts[t] - v;   // exclusive
    if (t == 255) *offs_total = ts[255];
}

__global__ __launch_bounds__(256) void k_scanC(int* __restrict__ offs,
                                               int* __restrict__ cursor,
                                               const int* __restrict__ bsums, int N) {
    int i = blockIdx.x * 256 + threadIdx.x;
    if (i >= N) return;
    int o = offs[i] + bsums[i >> 10];
    offs[i] = o;
    cursor[i] = o;
}

__global__ void k_scatter(const int* __restrict__ eidx, int* __restrict__ cursor,
                          int* __restrict__ src_s, int E) {
    int e = blockIdx.x * blockDim.x + threadIdx.x;
    if (e >= E) return;
    int d = eidx[E + e];
    int pos = atomicAdd(&cursor[d], 1);
    src_s[pos] = eidx[e];
}

// ---------------------------------------------------------------------------
// K4: fused attention + online softmax + aggregation. One wave per node.
// 4 edges per iteration: 16-lane group g computes edge (base+g)'s dot
// (8 bf16/lane, 4-step shfl reduce), alphas broadcast wave-wide, then 4
// independent bf16 xl-row gathers accumulate. All-bf16 gathers: 512B/edge.
// ---------------------------------------------------------------------------
__global__ __launch_bounds__(256) void k_agg(const unsigned int* __restrict__ xlb,
                                             const unsigned int* __restrict__ embb,
                                             const int* __restrict__ src_s,
                                             const int* __restrict__ offs,
                                             const float* __restrict__ bias,
                                             float* __restrict__ out, int N) {
    const int node = (int)((blockIdx.x * (size_t)blockDim.x + threadIdx.x) >> 6);
    const int lane = threadIdx.x & 63;
    if (node >= N) return;
    const int g = lane >> 4;        // edge slot 0..3
    const int sl = lane & 15;       // sub-lane within 16-group
    const int s0 = offs[node], s1 = offs[node + 1];

    // emb[node] in 16-lane layout: 8 bf16 (4 u32) per lane
    const uint4 eu = ((const uint4*)(embb + (size_t)node * (C / 2)))[sl];
    float ef[8];
    ef[0] = bflo(eu.x); ef[1] = bfhi(eu.x);
    ef[2] = bflo(eu.y); ef[3] = bfhi(eu.y);
    ef[4] = bflo(eu.z); ef[5] = bfhi(eu.z);
    ef[6] = bflo(eu.w); ef[7] = bfhi(eu.w);

    // self-loop logit = ||emb[node]||^2 (16-lane reduce; same in every group)
    float p = 0.0f;
#pragma unroll
    for (int i = 0; i < 8; ++i) p = fmaf(ef[i], ef[i], p);
#pragma unroll
    for (int o = 8; o >= 1; o >>= 1) p += __shfl_xor(p, o);

    float m = p;        // running max (self included)
    float d = 1.0f;     // exp(self - m) = 1
    const unsigned int xw = xlb[(size_t)node * (C / 2) + lane];
    float2 acc = {bflo(xw), bfhi(xw)};

    for (int base = s0; base < s1; base += 4) {
        const int rem = s1 - base;
        const int sg = (g < rem) ? src_s[base + g] : -1;
        const int sa = (sg >= 0) ? sg : node;

        // 16-lane dot: alpha_g = emb[node] . emb[src_g]
        const uint4 vu = ((const uint4*)(embb + (size_t)sa * (C / 2)))[sl];
        float a = 0.0f;
        a = fmaf(ef[0], bflo(vu.x), a); a = fmaf(ef[1], bfhi(vu.x), a);
        a = fmaf(ef[2], bflo(vu.y), a); a = fmaf(ef[3], bfhi(vu.y), a);
        a = fmaf(ef[4], bflo(vu.z), a); a = fmaf(ef[5], bfhi(vu.z), a);
        a = fmaf(ef[6], bflo(vu.w), a); a = fmaf(ef[7], bfhi(vu.w), a);
#pragma unroll
        for (int o = 8; o >= 1; o >>= 1) a += __shfl_xor(a, o);
        if (sg < 0) a = -INFINITY;

        // broadcast the 4 alphas + srcs wave-wide
        const float a0 = __shfl(a, 0),  a1 = __shfl(a, 16);
        const float a2 = __shfl(a, 32), a3 = __shfl(a, 48);
        const int   b0 = __shfl(sg, 0),  b1 = __shfl(sg, 16);
        const int   b2 = __shfl(sg, 32), b3 = __shfl(sg, 48);

        const float amax = fmaxf(fmaxf(a0, a1), fmaxf(a2, a3));
        if (amax > m) {                 // wave-uniform, rare
            const float cs = __expf(m - amax);
            d *= cs; acc.x *= cs; acc.y *= cs;
            m = amax;
        }
        const float w0 = __expf(a0 - m), w1 = __expf(a1 - m);
        const float w2 = __expf(a2 - m), w3 = __expf(a3 - m);
        d += (w0 + w1) + (w2 + w3);

        // 4 independent xl-row gathers (issue together), then accumulate
        const unsigned int u0 = xlb[(size_t)(b0 < 0 ? node : b0) * (C / 2) + lane];
        const unsigned int u1 = xlb[(size_t)(b1 < 0 ? node : b1) * (C / 2) + lane];
        const unsigned int u2 = xlb[(size_t)(b2 < 0 ? node : b2) * (C / 2) + lane];
        const unsigned int u3 = xlb[(size_t)(b3 < 0 ? node : b3) * (C / 2) + lane];
        acc.x = fmaf(w0, bflo(u0), acc.x); acc.y = fmaf(w0, bfhi(u0), acc.y);
        acc.x = fmaf(w1, bflo(u1), acc.x); acc.y = fmaf(w1, bfhi(u1), acc.y);
        acc.x = fmaf(w2, bflo(u2), acc.x); acc.y = fmaf(w2, bfhi(u2), acc.y);
        acc.x = fmaf(w3, bflo(u3), acc.x); acc.y = fmaf(w3, bfhi(u3), acc.y);
    }

    const float inv = 1.0f / (d + 1e-16f);
    const int c = lane * 2;
    float2 o2;
    o2.x = fmaf(acc.x, inv, bias[c]);
    o2.y = fmaf(acc.y, inv, bias[c + 1]);
    ((float2*)(out + (size_t)node * C))[lane] = o2;
}

// ---------------------------------------------------------------------------
// K5: per-channel BN stats (sum, sumsq) via block partials + atomics
// ---------------------------------------------------------------------------
__global__ __launch_bounds__(256) void k_bnstats(const float* __restrict__ out,
                                                 float* __restrict__ ssum,
                                                 float* __restrict__ ssq, int N) {
    const int c = threadIdx.x & 127, h = threadIdx.x >> 7;
    const int per = (N + gridDim.x - 1) / gridDim.x;
    const int r0 = blockIdx.x * per;
    const int r1 = min(r0 + per, N);
    float s = 0.0f, q = 0.0f;
    for (int r = r0 + h; r < r1; r += 2) {
        float v = out[(size_t)r * C + c];
        s += v;
        q = fmaf(v, v, q);
    }
    __shared__ float ls[256];
    ls[threadIdx.x] = s;
    __syncthreads();
    if (h == 0) atomicAdd(&ssum[c], ls[c] + ls[c + 128]);
    __syncthreads();
    ls[threadIdx.x] = q;
    __syncthreads();
    if (h == 0) atomicAdd(&ssq[c], ls[c] + ls[c + 128]);
}

// ---------------------------------------------------------------------------
// K6: in-place BN apply (training-mode batch stats, biased var) + ReLU
// ---------------------------------------------------------------------------
__global__ __launch_bounds__(256) void k_bnapply(float* __restrict__ out,
                                                 const float* __restrict__ ssum,
                                                 const float* __restrict__ ssq,
                                                 const float* __restrict__ gamma,
                                                 const float* __restrict__ beta,
                                                 int N) {
    const int idx = blockIdx.x * blockDim.x + threadIdx.x;   // float4 index
    const int total = N * (C / 4);
    if (idx >= total) return;
    const int c = (idx * 4) & 127;
    float4 v = ((const float4*)out)[idx];
    const float invN = 1.0f / (float)N;
    float r[4] = {v.x, v.y, v.z, v.w};
#pragma unroll
    for (int j = 0; j < 4; ++j) {
        float mu = ssum[c + j] * invN;
        float var = fmaf(-mu, mu, ssq[c + j] * invN);
        var = fmaxf(var, 0.0f);
        float sc = gamma[c + j] / sqrtf(var + 1e-5f);
        float val = fmaf(r[j] - mu, sc, beta[c + j]);
        r[j] = fmaxf(val, 0.0f);
    }
    float4 o = {r[0], r[1], r[2], r[3]};
    ((float4*)out)[idx] = o;
}

// ---------------------------------------------------------------------------
extern "C" void kernel_launch(void* const* d_in, const int* in_sizes, int n_in,
                              void* d_out, int out_size, void* d_ws, size_t ws_size,
                              hipStream_t stream) {
    const float* x     = (const float*)d_in[0];
    const int*   eidx  = (const int*)d_in[1];   // [2][E]
    const float* emb   = (const float*)d_in[2];
    const float* W     = (const float*)d_in[3];
    const float* bias  = (const float*)d_in[4];
    const float* gamma = (const float*)d_in[5];
    const float* beta  = (const float*)d_in[6];
    const int N = in_sizes[0] / C;
    const int E = in_sizes[1] / 2;
    float* out = (float*)d_out;

    char* ws = (char*)d_ws;
    size_t off = 0;
    auto alloc = [&](size_t bytes) -> void* {
        void* p = ws + off;
        off = (off + bytes + 255) & ~(size_t)255;
        return p;
    };
    unsigned short* xlb  = (unsigned short*)alloc((size_t)N * C * 2);
    unsigned int*   embb = (unsigned int*)  alloc((size_t)N * C * 2);
    int*   src_s   = (int*)  alloc((size_t)E * 4);
    int*   counts  = (int*)  alloc((size_t)N * 4);
    int*   cursor  = (int*)  alloc((size_t)N * 4);
    int*   offs    = (int*)  alloc((size_t)(N + 1) * 4);
    int*   bsums   = (int*)  alloc(256 * 4);
    float* ssum    = (float*)alloc(C * 4);
    float* ssq     = (float*)alloc(C * 4);

    const int nScanBlocks = (N + 1023) / 1024;   // 49 for N=50000

    hipMemsetAsync(counts, 0, (size_t)N * 4, stream);
    hipMemsetAsync(ssum, 0, C * 4, stream);
    hipMemsetAsync(ssq, 0, C * 4, stream);

    k_embcast<<<(N * (C / 8) + 255) / 256, 256, 0, stream>>>(emb, embb, N * (C / 8));
    k_gemm   <<<(N + 31) / 32,    256, 0, stream>>>(x, W, xlb, N);
    k_hist   <<<(E + 255) / 256,  256, 0, stream>>>(eidx, counts, E);
    k_scanA  <<<nScanBlocks,      256, 0, stream>>>(counts, offs, bsums, N);
    k_scanB  <<<1,                256, 0, stream>>>(bsums, offs + N, nScanBlocks);
    k_scanC  <<<(N + 255) / 256,  256, 0, stream>>>(offs, cursor, bsums, N);
    k_scatter<<<(E + 255) / 256,  256, 0, stream>>>(eidx, cursor, src_s, E);
    k_agg    <<<(int)(((size_t)N * 64 + 255) / 256), 256, 0, stream>>>(
                 (const unsigned int*)xlb, embb, src_s, offs, bias, out, N);
    k_bnstats<<<512,              256, 0, stream>>>(out, ssum, ssq, N);
    k_bnapply<<<(N * (C / 4) + 255) / 256, 256, 0, stream>>>(out, ssum, ssq, gamma, beta, N);
}

// Round 5
// 238.834 us; speedup vs baseline: 2.0236x; 1.0986x over previous
//
#include <hip/hip_runtime.h>
#include <math.h>

#define C 128  // IN_C == OUT_C == 128

typedef __attribute__((ext_vector_type(8))) short short8;
typedef __attribute__((ext_vector_type(4))) float f32x4;

static __device__ __forceinline__ unsigned short f2bf(float f) {
    unsigned int u = __float_as_uint(f);
    u += 0x7FFFu + ((u >> 16) & 1u);   // round-to-nearest-even
    return (unsigned short)(u >> 16);
}
static __device__ __forceinline__ float bflo(unsigned int u) {
    return __uint_as_float(u << 16);
}
static __device__ __forceinline__ float bfhi(unsigned int u) {
    return __uint_as_float(u & 0xFFFF0000u);
}

// ---------------------------------------------------------------------------
// K0: f32 -> packed bf16 (8 elems per thread). Used for emb, x, W.
// ---------------------------------------------------------------------------
__global__ __launch_bounds__(256) void k_cast(const float* __restrict__ in,
                                              unsigned int* __restrict__ outb,
                                              int total8) {
    int i = blockIdx.x * 256 + threadIdx.x;
    if (i >= total8) return;
    const float4 a = ((const float4*)in)[i * 2];
    const float4 b = ((const float4*)in)[i * 2 + 1];
    uint4 o;
    o.x = ((unsigned int)f2bf(a.y) << 16) | f2bf(a.x);
    o.y = ((unsigned int)f2bf(a.w) << 16) | f2bf(a.z);
    o.z = ((unsigned int)f2bf(b.y) << 16) | f2bf(b.x);
    o.w = ((unsigned int)f2bf(b.w) << 16) | f2bf(b.z);
    ((uint4*)outb)[i] = o;
}

// ---------------------------------------------------------------------------
// K1: xl = x @ W^T via MFMA bf16. Block = 4 waves, 64 rows (16/wave).
// A-frag: lane holds x[row0+(lane&15)][ (lane>>4)*8 + kb*32 .. +8 ] (uint4).
// B-frag: lane holds W[n0+(lane&15)][ same k slice ].
// C/D: col = lane&15, row = (lane>>4)*4 + reg  (verified layout).
// ---------------------------------------------------------------------------
__global__ __launch_bounds__(256) void k_gemm(const uint4* __restrict__ xb,
                                              const uint4* __restrict__ wb,
                                              unsigned short* __restrict__ xlb, int N) {
    const int lane = threadIdx.x & 63;
    const int wave = threadIdx.x >> 6;
    const int row0 = blockIdx.x * 64 + wave * 16;
    const int r = lane & 15, kg = lane >> 4;

    int arow = row0 + r;
    if (arow >= N) arow = N - 1;          // clamp (stores are guarded)
    const uint4* xrow = xb + (size_t)arow * 16;   // 16 uint4 = 128 bf16 per row
    short8 A[4];
#pragma unroll
    for (int kb = 0; kb < 4; ++kb)
        A[kb] = __builtin_bit_cast(short8, xrow[kb * 4 + kg]);

#pragma unroll
    for (int nt = 0; nt < 8; ++nt) {
        const uint4* wrow = wb + (size_t)(nt * 16 + r) * 16;
        f32x4 acc = {0.0f, 0.0f, 0.0f, 0.0f};
#pragma unroll
        for (int kb = 0; kb < 4; ++kb) {
            short8 B = __builtin_bit_cast(short8, wrow[kb * 4 + kg]);
            acc = __builtin_amdgcn_mfma_f32_16x16x32_bf16(A[kb], B, acc, 0, 0, 0);
        }
        const int orow = row0 + kg * 4;
        const int ocol = nt * 16 + r;
#pragma unroll
        for (int i = 0; i < 4; ++i)
            if (orow + i < N) xlb[(size_t)(orow + i) * C + ocol] = f2bf(acc[i]);
    }
}

// ---------------------------------------------------------------------------
// K3: CSR-by-dst build: histogram -> hierarchical exclusive scan -> scatter
// ---------------------------------------------------------------------------
__global__ void k_hist(const int* __restrict__ eidx, int* __restrict__ counts, int E) {
    int e = blockIdx.x * blockDim.x + threadIdx.x;
    if (e < E) atomicAdd(&counts[eidx[E + e]], 1);
}

__global__ __launch_bounds__(256) void k_scanA(const int* __restrict__ counts,
                                               int* __restrict__ offs,
                                               int* __restrict__ bsums, int N) {
    __shared__ int ts[256];
    const int t = threadIdx.x;
    const int base = blockIdx.x * 1024 + t * 4;
    int v[4];
    int s = 0;
#pragma unroll
    for (int j = 0; j < 4; ++j) {
        v[j] = (base + j < N) ? counts[base + j] : 0;
        s += v[j];
    }
    ts[t] = s;
    __syncthreads();
    for (int o = 1; o < 256; o <<= 1) {
        int u = (t >= o) ? ts[t - o] : 0;
        __syncthreads();
        ts[t] += u;
        __syncthreads();
    }
    int pref = (t == 0) ? 0 : ts[t - 1];
    if (t == 255) bsums[blockIdx.x] = ts[255];
#pragma unroll
    for (int j = 0; j < 4; ++j) {
        if (base + j < N) offs[base + j] = pref;
        pref += v[j];
    }
}

__global__ __launch_bounds__(256) void k_scanB(int* __restrict__ bsums,
                                               int* __restrict__ offs_total, int nb) {
    __shared__ int ts[256];
    const int t = threadIdx.x;
    int v = (t < nb) ? bsums[t] : 0;
    ts[t] = v;
    __syncthreads();
    for (int o = 1; o < 256; o <<= 1) {
        int u = (t >= o) ? ts[t - o] : 0;
        __syncthreads();
        ts[t] += u;
        __syncthreads();
    }
    if (t < nb) bsums[t] = ts[t] - v;   // exclusive
    if (t == 255) *offs_total = ts[255];
}

__global__ __launch_bounds__(256) void k_scanC(int* __restrict__ offs,
                                               int* __restrict__ cursor,
                                               const int* __restrict__ bsums, int N) {
    int i = blockIdx.x * 256 + threadIdx.x;
    if (i >= N) return;
    int o = offs[i] + bsums[i >> 10];
    offs[i] = o;
    cursor[i] = o;
}

__global__ void k_scatter(const int* __restrict__ eidx, int* __restrict__ cursor,
                          int* __restrict__ src_s, int E) {
    int e = blockIdx.x * blockDim.x + threadIdx.x;
    if (e >= E) return;
    int d = eidx[E + e];
    int pos = atomicAdd(&cursor[d], 1);
    src_s[pos] = eidx[e];
}

// ---------------------------------------------------------------------------
// K4: fused attention + online softmax + aggregation. One wave per node.
// 8 edges/iter: 8-lane group g computes edge (base+g)'s dot (16 bf16/lane,
// 3-step shfl reduce), alphas broadcast wave-wide, 8 xlb gathers in flight.
// ---------------------------------------------------------------------------
__global__ __launch_bounds__(256) void k_agg(const unsigned int* __restrict__ xlb,
                                             const unsigned int* __restrict__ embb,
                                             const int* __restrict__ src_s,
                                             const int* __restrict__ offs,
                                             const float* __restrict__ bias,
                                             float* __restrict__ out, int N) {
    const int node = (int)((blockIdx.x * (size_t)blockDim.x + threadIdx.x) >> 6);
    const int lane = threadIdx.x & 63;
    if (node >= N) return;
    const int g = lane >> 3;        // edge slot 0..7
    const int sl = lane & 7;        // sub-lane within 8-group
    const int s0 = offs[node], s1 = offs[node + 1];

    // emb[node]: 16 bf16 per lane (2 uint4) in 8-lane layout
    const uint4* erow = (const uint4*)(embb + (size_t)node * (C / 2));
    const uint4 e0 = erow[sl * 2], e1 = erow[sl * 2 + 1];
    float ef[16];
    ef[0]  = bflo(e0.x); ef[1]  = bfhi(e0.x); ef[2]  = bflo(e0.y); ef[3]  = bfhi(e0.y);
    ef[4]  = bflo(e0.z); ef[5]  = bfhi(e0.z); ef[6]  = bflo(e0.w); ef[7]  = bfhi(e0.w);
    ef[8]  = bflo(e1.x); ef[9]  = bfhi(e1.x); ef[10] = bflo(e1.y); ef[11] = bfhi(e1.y);
    ef[12] = bflo(e1.z); ef[13] = bfhi(e1.z); ef[14] = bflo(e1.w); ef[15] = bfhi(e1.w);

    // self-loop logit = ||emb[node]||^2 (8-lane reduce; same in every group)
    float p = 0.0f;
#pragma unroll
    for (int i = 0; i < 16; ++i) p = fmaf(ef[i], ef[i], p);
#pragma unroll
    for (int o = 4; o >= 1; o >>= 1) p += __shfl_xor(p, o);

    float m = p;        // running max (self included)
    float d = 1.0f;     // exp(self - m) = 1
    const unsigned int xw = xlb[(size_t)node * (C / 2) + lane];
    float2 acc = {bflo(xw), bfhi(xw)};

    for (int base = s0; base < s1; base += 8) {
        int mys = -1;
        if (lane < 8 && base + lane < s1) mys = src_s[base + lane];
        const int sg = __shfl(mys, g);
        const int sa = (sg >= 0) ? sg : node;

        // 8-lane dot: alpha_g = emb[node] . emb[src_g]
        const uint4* vrow = (const uint4*)(embb + (size_t)sa * (C / 2));
        const uint4 v0 = vrow[sl * 2], v1 = vrow[sl * 2 + 1];
        float a = 0.0f;
        a = fmaf(ef[0],  bflo(v0.x), a); a = fmaf(ef[1],  bfhi(v0.x), a);
        a = fmaf(ef[2],  bflo(v0.y), a); a = fmaf(ef[3],  bfhi(v0.y), a);
        a = fmaf(ef[4],  bflo(v0.z), a); a = fmaf(ef[5],  bfhi(v0.z), a);
        a = fmaf(ef[6],  bflo(v0.w), a); a = fmaf(ef[7],  bfhi(v0.w), a);
        a = fmaf(ef[8],  bflo(v1.x), a); a = fmaf(ef[9],  bfhi(v1.x), a);
        a = fmaf(ef[10], bflo(v1.y), a); a = fmaf(ef[11], bfhi(v1.y), a);
        a = fmaf(ef[12], bflo(v1.z), a); a = fmaf(ef[13], bfhi(v1.z), a);
        a = fmaf(ef[14], bflo(v1.w), a); a = fmaf(ef[15], bfhi(v1.w), a);
#pragma unroll
        for (int o = 4; o >= 1; o >>= 1) a += __shfl_xor(a, o);
        if (sg < 0) a = -INFINITY;

        // broadcast 8 alphas + srcs wave-wide
        float ag[8]; int bg[8];
#pragma unroll
        for (int j = 0; j < 8; ++j) {
            ag[j] = __shfl(a, j * 8);
            bg[j] = __shfl(mys, j);
        }
        const float amax = fmaxf(fmaxf(fmaxf(ag[0], ag[1]), fmaxf(ag[2], ag[3])),
                                 fmaxf(fmaxf(ag[4], ag[5]), fmaxf(ag[6], ag[7])));
        if (amax > m) {                 // wave-uniform, rare
            const float cs = __expf(m - amax);
            d *= cs; acc.x *= cs; acc.y *= cs;
            m = amax;
        }
        float w[8]; unsigned int u[8];
#pragma unroll
        for (int j = 0; j < 8; ++j) {
            w[j] = __expf(ag[j] - m);
            u[j] = xlb[(size_t)(bg[j] < 0 ? node : bg[j]) * (C / 2) + lane];
        }
#pragma unroll
        for (int j = 0; j < 8; ++j) {
            d += w[j];
            acc.x = fmaf(w[j], bflo(u[j]), acc.x);
            acc.y = fmaf(w[j], bfhi(u[j]), acc.y);
        }
    }

    const float inv = 1.0f / (d + 1e-16f);
    const int c = lane * 2;
    float2 o2;
    o2.x = fmaf(acc.x, inv, bias[c]);
    o2.y = fmaf(acc.y, inv, bias[c + 1]);
    ((float2*)(out + (size_t)node * C))[lane] = o2;
}

// ---------------------------------------------------------------------------
// K5: BN stats — grid-stride float4; each thread owns a fixed channel quad
// (stride is a multiple of 32 float4s), LDS-reduce, 8 atomics per channel set.
// ---------------------------------------------------------------------------
__global__ __launch_bounds__(256) void k_bnstats(const float* __restrict__ out,
                                                 float* __restrict__ ssum,
                                                 float* __restrict__ ssq, int N) {
    const int tid = threadIdx.x;
    const int total4 = N * (C / 4);
    const int stride = gridDim.x * 256;          // multiple of 32
    float4 s4 = {0, 0, 0, 0}, q4 = {0, 0, 0, 0};
    for (int i = blockIdx.x * 256 + tid; i < total4; i += stride) {
        float4 v = ((const float4*)out)[i];
        s4.x += v.x; s4.y += v.y; s4.z += v.z; s4.w += v.w;
        q4.x = fmaf(v.x, v.x, q4.x); q4.y = fmaf(v.y, v.y, q4.y);
        q4.z = fmaf(v.z, v.z, q4.z); q4.w = fmaf(v.w, v.w, q4.w);
    }
    __shared__ float4 lsum[256];
    __shared__ float4 lsq[256];
    lsum[tid] = s4; lsq[tid] = q4;
    __syncthreads();
    if (tid < 32) {
        float4 S = lsum[tid], Q = lsq[tid];
#pragma unroll
        for (int j = 1; j < 8; ++j) {
            float4 a = lsum[tid + 32 * j], b = lsq[tid + 32 * j];
            S.x += a.x; S.y += a.y; S.z += a.z; S.w += a.w;
            Q.x += b.x; Q.y += b.y; Q.z += b.z; Q.w += b.w;
        }
        const int c = tid * 4;
        atomicAdd(&ssum[c], S.x);     atomicAdd(&ssum[c + 1], S.y);
        atomicAdd(&ssum[c + 2], S.z); atomicAdd(&ssum[c + 3], S.w);
        atomicAdd(&ssq[c], Q.x);      atomicAdd(&ssq[c + 1], Q.y);
        atomicAdd(&ssq[c + 2], Q.z);  atomicAdd(&ssq[c + 3], Q.w);
    }
}

// ---------------------------------------------------------------------------
// K6: in-place BN apply (training-mode batch stats, biased var) + ReLU
// ---------------------------------------------------------------------------
__global__ __launch_bounds__(256) void k_bnapply(float* __restrict__ out,
                                                 const float* __restrict__ ssum,
                                                 const float* __restrict__ ssq,
                                                 const float* __restrict__ gamma,
                                                 const float* __restrict__ beta,
                                                 int N) {
    const int idx = blockIdx.x * blockDim.x + threadIdx.x;   // float4 index
    const int total = N * (C / 4);
    if (idx >= total) return;
    const int c = (idx * 4) & 127;
    float4 v = ((const float4*)out)[idx];
    const float invN = 1.0f / (float)N;
    float r[4] = {v.x, v.y, v.z, v.w};
#pragma unroll
    for (int j = 0; j < 4; ++j) {
        float mu = ssum[c + j] * invN;
        float var = fmaf(-mu, mu, ssq[c + j] * invN);
        var = fmaxf(var, 0.0f);
        float sc = gamma[c + j] / sqrtf(var + 1e-5f);
        float val = fmaf(r[j] - mu, sc, beta[c + j]);
        r[j] = fmaxf(val, 0.0f);
    }
    float4 o = {r[0], r[1], r[2], r[3]};
    ((float4*)out)[idx] = o;
}

// ---------------------------------------------------------------------------
extern "C" void kernel_launch(void* const* d_in, const int* in_sizes, int n_in,
                              void* d_out, int out_size, void* d_ws, size_t ws_size,
                              hipStream_t stream) {
    const float* x     = (const float*)d_in[0];
    const int*   eidx  = (const int*)d_in[1];   // [2][E]
    const float* emb   = (const float*)d_in[2];
    const float* W     = (const float*)d_in[3];
    const float* bias  = (const float*)d_in[4];
    const float* gamma = (const float*)d_in[5];
    const float* beta  = (const float*)d_in[6];
    const int N = in_sizes[0] / C;
    const int E = in_sizes[1] / 2;
    float* out = (float*)d_out;

    char* ws = (char*)d_ws;
    size_t off = 0;
    auto alloc = [&](size_t bytes) -> void* {
        void* p = ws + off;
        off = (off + bytes + 255) & ~(size_t)255;
        return p;
    };
    unsigned short* xlb  = (unsigned short*)alloc((size_t)N * C * 2);
    unsigned int*   embb = (unsigned int*)  alloc((size_t)N * C * 2);
    unsigned int*   xb   = (unsigned int*)  alloc((size_t)N * C * 2);
    unsigned int*   wb   = (unsigned int*)  alloc((size_t)C * C * 2);
    int*   src_s   = (int*)  alloc((size_t)E * 4);
    int*   cursor  = (int*)  alloc((size_t)N * 4);
    int*   offs    = (int*)  alloc((size_t)(N + 1) * 4);
    int*   bsums   = (int*)  alloc(256 * 4);
    // contiguous zero-init region: counts + ssum + ssq
    char*  zbase   = (char*)alloc(0);
    int*   counts  = (int*)  alloc((size_t)N * 4);
    float* ssum    = (float*)alloc(C * 4);
    float* ssq     = (float*)alloc(C * 4);
    size_t zbytes  = (char*)ws + off - zbase;

    const int nScanBlocks = (N + 1023) / 1024;   // 49 for N=50000

    hipMemsetAsync(zbase, 0, zbytes, stream);

    k_cast   <<<(N * (C / 8) + 255) / 256, 256, 0, stream>>>(emb, embb, N * (C / 8));
    k_cast   <<<(N * (C / 8) + 255) / 256, 256, 0, stream>>>(x, xb, N * (C / 8));
    k_cast   <<<(C * (C / 8) + 255) / 256, 256, 0, stream>>>(W, wb, C * (C / 8));
    k_gemm   <<<(N + 63) / 64,    256, 0, stream>>>((const uint4*)xb, (const uint4*)wb, xlb, N);
    k_hist   <<<(E + 255) / 256,  256, 0, stream>>>(eidx, counts, E);
    k_scanA  <<<nScanBlocks,      256, 0, stream>>>(counts, offs, bsums, N);
    k_scanB  <<<1,                256, 0, stream>>>(bsums, offs + N, nScanBlocks);
    k_scanC  <<<(N + 255) / 256,  256, 0, stream>>>(offs, cursor, bsums, N);
    k_scatter<<<(E + 255) / 256,  256, 0, stream>>>(eidx, cursor, src_s, E);
    k_agg    <<<(int)(((size_t)N * 64 + 255) / 256), 256, 0, stream>>>(
                 (const unsigned int*)xlb, embb, src_s, offs, bias, out, N);
    k_bnstats<<<256,              256, 0, stream>>>(out, ssum, ssq, N);
    k_bnapply<<<(N * (C / 4) + 255) / 256, 256, 0, stream>>>(out, ssum, ssq, gamma, beta, N);
}